// Round 2
// baseline (74.988 us; speedup 1.0000x reference)
//
#include <hip/hip_runtime.h>
#include <hip/hip_bf16.h>
#include <math.h>

#define DEPTH    11
#define NNODES   4095
#define DIN      768
#define NTOK     8192

// ---------------------------------------------------------------------------
// Transpose + bf16-quantize w_out [768][4095] f32  ->  wT [4095][768] bf16.
// ---------------------------------------------------------------------------
__global__ __launch_bounds__(256) void fff_transpose_bf16(const float* __restrict__ src,
                                                          __hip_bfloat16* __restrict__ dst) {
    __shared__ float tile[32][33];
    const int n0 = blockIdx.x * 32;  // node dim (4095)
    const int j0 = blockIdx.y * 32;  // feature dim (768)
    const int tx = threadIdx.x, ty = threadIdx.y;
#pragma unroll
    for (int i = 0; i < 32; i += 8) {
        const int j = j0 + ty + i;
        const int n = n0 + tx;
        if (n < NNODES) tile[ty + i][tx] = src[(size_t)j * NNODES + n];
    }
    __syncthreads();
#pragma unroll
    for (int i = 0; i < 32; i += 8) {
        const int n = n0 + ty + i;
        const int j = j0 + tx;
        if (n < NNODES) dst[(size_t)n * DIN + j] = __float2bfloat16(tile[tx][ty + i]);
    }
}

__device__ __forceinline__ float bf_lo(unsigned u) {
    union { unsigned v; float f; } c; c.v = u << 16; return c.f;
}
__device__ __forceinline__ float bf_hi(unsigned u) {
    union { unsigned v; float f; } c; c.v = u & 0xffff0000u; return c.f;
}

// ---------------------------------------------------------------------------
// One wave per token. Phase 1: walk the 12-node path (serial chain, f64 dot
// for decision fidelity), recording g[d] and node[d] in statically-indexed
// registers. Phase 2: gather-accumulate all 12 wT rows with 36 independent
// bf16 loads (deep MLP) and write the output row.
// ---------------------------------------------------------------------------
__global__ __launch_bounds__(256, 4) void fff_walk_gather(const float* __restrict__ x,
                                                          const float* __restrict__ w_in,
                                                          const __hip_bfloat16* __restrict__ wT,
                                                          float* __restrict__ out) {
    const int token = (int)((blockIdx.x * blockDim.x + threadIdx.x) >> 6);
    const int lane  = (int)(threadIdx.x & 63);

    // Lane owns float4 chunks lane + 64*k (k = 0..2): 768 = 64 * 3 * 4.
    const float4* xr = reinterpret_cast<const float4*>(x + (size_t)token * DIN);
    float4 xv[3];
#pragma unroll
    for (int k = 0; k < 3; ++k) xv[k] = xr[lane + 64 * k];

    float g[DEPTH + 1];
    int   nd[DEPTH + 1];
    int   cur = 0;

#pragma unroll
    for (int d = 0; d <= DEPTH; ++d) {
        const float4* wr = reinterpret_cast<const float4*>(w_in + (size_t)cur * DIN);
        // three independent f64 sub-chains (products are exact in f64)
        double p0 = 0.0, p1 = 0.0, p2 = 0.0;
        {
            const float4 w0 = wr[lane];
            const float4 w1 = wr[lane + 64];
            const float4 w2 = wr[lane + 128];
            p0 += (double)xv[0].x * w0.x; p0 += (double)xv[0].y * w0.y;
            p0 += (double)xv[0].z * w0.z; p0 += (double)xv[0].w * w0.w;
            p1 += (double)xv[1].x * w1.x; p1 += (double)xv[1].y * w1.y;
            p1 += (double)xv[1].z * w1.z; p1 += (double)xv[1].w * w1.w;
            p2 += (double)xv[2].x * w2.x; p2 += (double)xv[2].y * w2.y;
            p2 += (double)xv[2].z * w2.z; p2 += (double)xv[2].w * w2.w;
        }
        double part = (p0 + p1) + p2;
#pragma unroll
        for (int off = 32; off >= 1; off >>= 1) part += __shfl_xor(part, off);

        const float logit = (float)part;
        g[d]  = 0.5f * logit * (1.0f + erff(logit * 0.7071067811865476f));
        nd[d] = cur;
        if (d < DEPTH) cur = 2 * cur + 1 + (part > 0.0 ? 1 : 0);
    }

    // ---- Phase 2: gather. Row = 768 bf16 = 192 uint2; lane covers uint2
    // index lane + 64*k (k = 0..2) -> bf16 elems [256*k + 4*lane, +4).
    float acc[12];
#pragma unroll
    for (int i = 0; i < 12; ++i) acc[i] = 0.f;

#pragma unroll
    for (int d = 0; d <= DEPTH; ++d) {
        const uint2* row = reinterpret_cast<const uint2*>(wT + (size_t)nd[d] * DIN);
        const float gg = g[d];
#pragma unroll
        for (int k = 0; k < 3; ++k) {
            const uint2 v = row[lane + 64 * k];
            acc[k * 4 + 0] = fmaf(gg, bf_lo(v.x), acc[k * 4 + 0]);
            acc[k * 4 + 1] = fmaf(gg, bf_hi(v.x), acc[k * 4 + 1]);
            acc[k * 4 + 2] = fmaf(gg, bf_lo(v.y), acc[k * 4 + 2]);
            acc[k * 4 + 3] = fmaf(gg, bf_hi(v.y), acc[k * 4 + 3]);
        }
    }

    float4* orow = reinterpret_cast<float4*>(out + (size_t)token * DIN);
#pragma unroll
    for (int k = 0; k < 3; ++k)
        orow[k * 64 + lane] = make_float4(acc[k * 4 + 0], acc[k * 4 + 1],
                                          acc[k * 4 + 2], acc[k * 4 + 3]);
}

// ---------------------------------------------------------------------------
// Fallback (ws too small): round-1 fused kernel with strided f32 w_out reads.
// ---------------------------------------------------------------------------
__global__ __launch_bounds__(256) void fff_fused_fallback(const float* __restrict__ x,
                                                          const float* __restrict__ w_in,
                                                          const float* __restrict__ w_o,
                                                          float* __restrict__ out) {
    const int token = (int)((blockIdx.x * blockDim.x + threadIdx.x) >> 6);
    const int lane  = (int)(threadIdx.x & 63);

    const float4* xr = reinterpret_cast<const float4*>(x + (size_t)token * DIN);
    float4 xv[3];
#pragma unroll
    for (int k = 0; k < 3; ++k) xv[k] = xr[lane + 64 * k];
    float4 acc[3];
#pragma unroll
    for (int k = 0; k < 3; ++k) acc[k] = make_float4(0.f, 0.f, 0.f, 0.f);

    int cur = 0;
#pragma unroll
    for (int d = 0; d <= DEPTH; ++d) {
        const float4* wr = reinterpret_cast<const float4*>(w_in + (size_t)cur * DIN);
        double part = 0.0;
#pragma unroll
        for (int k = 0; k < 3; ++k) {
            const float4 w = wr[lane + 64 * k];
            part += (double)xv[k].x * w.x; part += (double)xv[k].y * w.y;
            part += (double)xv[k].z * w.z; part += (double)xv[k].w * w.w;
        }
#pragma unroll
        for (int off = 32; off >= 1; off >>= 1) part += __shfl_xor(part, off);
        const float logit = (float)part;
        const float gg = 0.5f * logit * (1.0f + erff(logit * 0.7071067811865476f));
#pragma unroll
        for (int k = 0; k < 3; ++k) {
            const int j = (lane + 64 * k) * 4;
            acc[k].x = fmaf(gg, w_o[(size_t)(j + 0) * NNODES + cur], acc[k].x);
            acc[k].y = fmaf(gg, w_o[(size_t)(j + 1) * NNODES + cur], acc[k].y);
            acc[k].z = fmaf(gg, w_o[(size_t)(j + 2) * NNODES + cur], acc[k].z);
            acc[k].w = fmaf(gg, w_o[(size_t)(j + 3) * NNODES + cur], acc[k].w);
        }
        if (d < DEPTH) cur = 2 * cur + 1 + (part > 0.0 ? 1 : 0);
    }
    float4* orow = reinterpret_cast<float4*>(out + (size_t)token * DIN);
#pragma unroll
    for (int k = 0; k < 3; ++k) orow[lane + 64 * k] = acc[k];
}

extern "C" void kernel_launch(void* const* d_in, const int* in_sizes, int n_in,
                              void* d_out, int out_size, void* d_ws, size_t ws_size,
                              hipStream_t stream) {
    const float* x     = (const float*)d_in[0];   // [8192, 768]
    const float* w_in  = (const float*)d_in[1];   // [4095, 768]
    const float* w_out = (const float*)d_in[2];   // [768, 4095]
    float*       out   = (float*)d_out;           // [8192, 768]

    const size_t need = (size_t)NNODES * DIN * sizeof(__hip_bfloat16);  // 6.29 MB
    const dim3 mb(256);
    const dim3 mg(NTOK / 4);  // 4 waves/block, 1 token/wave, 2048 blocks

    if (ws_size >= need) {
        __hip_bfloat16* wT = (__hip_bfloat16*)d_ws;
        dim3 tb(32, 8);
        dim3 tg((NNODES + 31) / 32, DIN / 32);
        hipLaunchKernelGGL(fff_transpose_bf16, tg, tb, 0, stream, w_out, wT);
        hipLaunchKernelGGL(fff_walk_gather, mg, mb, 0, stream, x, w_in, wT, out);
    } else {
        hipLaunchKernelGGL(fff_fused_fallback, mg, mb, 0, stream, x, w_in, w_out, out);
    }
}

// Round 3
// 57.516 us; speedup vs baseline: 1.3038x; 1.3038x over previous
//
#include <hip/hip_runtime.h>
#include <hip/hip_bf16.h>
#include <math.h>

#define DEPTH    11
#define NNODES   4095
#define DIN      768
#define NTOK     8192

// ---------------------------------------------------------------------------
// Transpose + bf16-quantize w_out [768][4095] f32  ->  wT [4095][768] bf16.
// ---------------------------------------------------------------------------
__global__ __launch_bounds__(256) void fff_transpose_bf16(const float* __restrict__ src,
                                                          __hip_bfloat16* __restrict__ dst) {
    __shared__ float tile[32][33];
    const int n0 = blockIdx.x * 32;  // node dim (4095)
    const int j0 = blockIdx.y * 32;  // feature dim (768)
    const int tx = threadIdx.x, ty = threadIdx.y;
#pragma unroll
    for (int i = 0; i < 32; i += 8) {
        const int j = j0 + ty + i;
        const int n = n0 + tx;
        if (n < NNODES) tile[ty + i][tx] = src[(size_t)j * NNODES + n];
    }
    __syncthreads();
#pragma unroll
    for (int i = 0; i < 32; i += 8) {
        const int n = n0 + ty + i;
        const int j = j0 + tx;
        if (n < NNODES) dst[(size_t)n * DIN + j] = __float2bfloat16(tile[tx][ty + i]);
    }
}

__device__ __forceinline__ float bf_lo(unsigned u) {
    union { unsigned v; float f; } c; c.v = u << 16; return c.f;
}
__device__ __forceinline__ float bf_hi(unsigned u) {
    union { unsigned v; float f; } c; c.v = u & 0xffff0000u; return c.f;
}

// ---------------------------------------------------------------------------
// Walk kernel: one 64-lane wave per token. Serial 12-level tree walk with
// SPECULATIVE PREFETCH of both children rows: loads for level d+1 are issued
// before level d's dot/reduce, so L2/L3 latency hides under compute. The
// decision then just selects the already-loaded row via cndmask.
// Dot arithmetic is bit-identical to round 2 (3-chain f64, same reduce order).
// Writes nd[12], g[12] per token.
// ---------------------------------------------------------------------------
__global__ __launch_bounds__(256) void fff_walk(const float* __restrict__ x,
                                                const float* __restrict__ w_in,
                                                int* __restrict__ nd_out,
                                                float* __restrict__ g_out) {
    const int token = (int)((blockIdx.x * blockDim.x + threadIdx.x) >> 6);
    const int lane  = (int)(threadIdx.x & 63);

    // Lane owns float4 chunks lane + 64*k (k = 0..2): 768 = 64 * 3 * 4.
    const float4* xr = reinterpret_cast<const float4*>(x + (size_t)token * DIN);
    float4 xv0 = xr[lane], xv1 = xr[lane + 64], xv2 = xr[lane + 128];

    // current row registers (root row 0)
    const float4* r0 = reinterpret_cast<const float4*>(w_in);
    float4 c0 = r0[lane], c1 = r0[lane + 64], c2 = r0[lane + 128];

    int cur = 0;
#pragma unroll
    for (int d = 0; d <= DEPTH; ++d) {
        // ---- speculative prefetch of both children (issued before the dot) ----
        float4 l0, l1, l2, rr0, rr1, rr2;
        if (d < DEPTH) {
            const float4* cl = reinterpret_cast<const float4*>(w_in + (size_t)(2 * cur + 1) * DIN);
            const float4* cr = reinterpret_cast<const float4*>(w_in + (size_t)(2 * cur + 2) * DIN);
            l0 = cl[lane]; l1 = cl[lane + 64]; l2 = cl[lane + 128];
            rr0 = cr[lane]; rr1 = cr[lane + 64]; rr2 = cr[lane + 128];
        }

        // ---- f64 dot of current row (regs already resident) ----
        double p0 = 0.0, p1 = 0.0, p2 = 0.0;
        p0 += (double)xv0.x * c0.x; p0 += (double)xv0.y * c0.y;
        p0 += (double)xv0.z * c0.z; p0 += (double)xv0.w * c0.w;
        p1 += (double)xv1.x * c1.x; p1 += (double)xv1.y * c1.y;
        p1 += (double)xv1.z * c1.z; p1 += (double)xv1.w * c1.w;
        p2 += (double)xv2.x * c2.x; p2 += (double)xv2.y * c2.y;
        p2 += (double)xv2.z * c2.z; p2 += (double)xv2.w * c2.w;
        double part = (p0 + p1) + p2;
#pragma unroll
        for (int off = 32; off >= 1; off >>= 1) part += __shfl_xor(part, off);

        const float logit = (float)part;
        const float g = 0.5f * logit * (1.0f + erff(logit * 0.7071067811865476f));
        if (lane == 0) {
            g_out[token * 12 + d]  = g;
            nd_out[token * 12 + d] = cur;
        }

        // ---- select prefetched child ----
        if (d < DEPTH) {
            const bool right = (part > 0.0);
            c0 = right ? rr0 : l0;
            c1 = right ? rr1 : l1;
            c2 = right ? rr2 : l2;
            cur = 2 * cur + 1 + (right ? 1 : 0);
        }
    }
}

// ---------------------------------------------------------------------------
// Gather kernel: one wave per token; 36 fully independent bf16 row loads.
// ---------------------------------------------------------------------------
__global__ __launch_bounds__(256) void fff_gather(const __hip_bfloat16* __restrict__ wT,
                                                  const int* __restrict__ nd_in,
                                                  const float* __restrict__ g_in,
                                                  float* __restrict__ out) {
    const int token = (int)((blockIdx.x * blockDim.x + threadIdx.x) >> 6);
    const int lane  = (int)(threadIdx.x & 63);

    // broadcast path metadata to all lanes
    float gv = 0.f; int nv = 0;
    if (lane < 12) {
        gv = g_in[token * 12 + lane];
        nv = nd_in[token * 12 + lane];
    }

    float acc[12];
#pragma unroll
    for (int i = 0; i < 12; ++i) acc[i] = 0.f;

#pragma unroll
    for (int d = 0; d <= DEPTH; ++d) {
        const float gg = __shfl(gv, d);
        const int   nn = __shfl(nv, d);
        const uint2* row = reinterpret_cast<const uint2*>(wT + (size_t)nn * DIN);
#pragma unroll
        for (int k = 0; k < 3; ++k) {
            const uint2 v = row[lane + 64 * k];
            acc[k * 4 + 0] = fmaf(gg, bf_lo(v.x), acc[k * 4 + 0]);
            acc[k * 4 + 1] = fmaf(gg, bf_hi(v.x), acc[k * 4 + 1]);
            acc[k * 4 + 2] = fmaf(gg, bf_lo(v.y), acc[k * 4 + 2]);
            acc[k * 4 + 3] = fmaf(gg, bf_hi(v.y), acc[k * 4 + 3]);
        }
    }

    float4* orow = reinterpret_cast<float4*>(out + (size_t)token * DIN);
#pragma unroll
    for (int k = 0; k < 3; ++k)
        orow[k * 64 + lane] = make_float4(acc[k * 4 + 0], acc[k * 4 + 1],
                                          acc[k * 4 + 2], acc[k * 4 + 3]);
}

// ---------------------------------------------------------------------------
// Fallback (ws too small): round-1 fused kernel with strided f32 w_out reads.
// ---------------------------------------------------------------------------
__global__ __launch_bounds__(256) void fff_fused_fallback(const float* __restrict__ x,
                                                          const float* __restrict__ w_in,
                                                          const float* __restrict__ w_o,
                                                          float* __restrict__ out) {
    const int token = (int)((blockIdx.x * blockDim.x + threadIdx.x) >> 6);
    const int lane  = (int)(threadIdx.x & 63);

    const float4* xr = reinterpret_cast<const float4*>(x + (size_t)token * DIN);
    float4 xv[3];
#pragma unroll
    for (int k = 0; k < 3; ++k) xv[k] = xr[lane + 64 * k];
    float4 acc[3];
#pragma unroll
    for (int k = 0; k < 3; ++k) acc[k] = make_float4(0.f, 0.f, 0.f, 0.f);

    int cur = 0;
#pragma unroll
    for (int d = 0; d <= DEPTH; ++d) {
        const float4* wr = reinterpret_cast<const float4*>(w_in + (size_t)cur * DIN);
        double part = 0.0;
#pragma unroll
        for (int k = 0; k < 3; ++k) {
            const float4 w = wr[lane + 64 * k];
            part += (double)xv[k].x * w.x; part += (double)xv[k].y * w.y;
            part += (double)xv[k].z * w.z; part += (double)xv[k].w * w.w;
        }
#pragma unroll
        for (int off = 32; off >= 1; off >>= 1) part += __shfl_xor(part, off);
        const float logit = (float)part;
        const float gg = 0.5f * logit * (1.0f + erff(logit * 0.7071067811865476f));
#pragma unroll
        for (int k = 0; k < 3; ++k) {
            const int j = (lane + 64 * k) * 4;
            acc[k].x = fmaf(gg, w_o[(size_t)(j + 0) * NNODES + cur], acc[k].x);
            acc[k].y = fmaf(gg, w_o[(size_t)(j + 1) * NNODES + cur], acc[k].y);
            acc[k].z = fmaf(gg, w_o[(size_t)(j + 2) * NNODES + cur], acc[k].z);
            acc[k].w = fmaf(gg, w_o[(size_t)(j + 3) * NNODES + cur], acc[k].w);
        }
        if (d < DEPTH) cur = 2 * cur + 1 + (part > 0.0 ? 1 : 0);
    }
    float4* orow = reinterpret_cast<float4*>(out + (size_t)token * DIN);
#pragma unroll
    for (int k = 0; k < 3; ++k) orow[lane + 64 * k] = acc[k];
}

extern "C" void kernel_launch(void* const* d_in, const int* in_sizes, int n_in,
                              void* d_out, int out_size, void* d_ws, size_t ws_size,
                              hipStream_t stream) {
    const float* x     = (const float*)d_in[0];   // [8192, 768]
    const float* w_in  = (const float*)d_in[1];   // [4095, 768]
    const float* w_out = (const float*)d_in[2];   // [768, 4095]
    float*       out   = (float*)d_out;           // [8192, 768]

    const size_t wT_bytes = (size_t)NNODES * DIN * sizeof(__hip_bfloat16);  // 6,289,920
    const size_t nd_bytes = (size_t)NTOK * 12 * sizeof(int);                // 393,216
    const size_t g_bytes  = (size_t)NTOK * 12 * sizeof(float);              // 393,216
    const size_t need = wT_bytes + nd_bytes + g_bytes;                      // ~7.08 MB

    const dim3 mb(256);
    const dim3 mg(NTOK / 4);  // 4 waves/block, 1 token/wave, 2048 blocks

    if (ws_size >= need) {
        char* ws = (char*)d_ws;
        __hip_bfloat16* wT = (__hip_bfloat16*)ws;
        int*   nd = (int*)(ws + wT_bytes);
        float* g  = (float*)(ws + wT_bytes + nd_bytes);

        dim3 tb(32, 8);
        dim3 tg((NNODES + 31) / 32, DIN / 32);
        hipLaunchKernelGGL(fff_transpose_bf16, tg, tb, 0, stream, w_out, wT);
        hipLaunchKernelGGL(fff_walk,   mg, mb, 0, stream, x, w_in, nd, g);
        hipLaunchKernelGGL(fff_gather, mg, mb, 0, stream, wT, nd, g, out);
    } else {
        hipLaunchKernelGGL(fff_fused_fallback, mg, mb, 0, stream, x, w_in, w_out, out);
    }
}

// Round 4
// 47.154 us; speedup vs baseline: 1.5903x; 1.2198x over previous
//
#include <hip/hip_runtime.h>
#include <hip/hip_bf16.h>
#include <math.h>

#define DEPTH    11
#define NNODES   4095
#define DIN      768
#define NTOK     8192

// ---------------------------------------------------------------------------
// Transpose + bf16-quantize w_out [768][4095] f32  ->  wT [4095][768] bf16.
// ---------------------------------------------------------------------------
__global__ __launch_bounds__(256) void fff_transpose_bf16(const float* __restrict__ src,
                                                          __hip_bfloat16* __restrict__ dst) {
    __shared__ float tile[32][33];
    const int n0 = blockIdx.x * 32;  // node dim (4095)
    const int j0 = blockIdx.y * 32;  // feature dim (768)
    const int tx = threadIdx.x, ty = threadIdx.y;
#pragma unroll
    for (int i = 0; i < 32; i += 8) {
        const int j = j0 + ty + i;
        const int n = n0 + tx;
        if (n < NNODES) tile[ty + i][tx] = src[(size_t)j * NNODES + n];
    }
    __syncthreads();
#pragma unroll
    for (int i = 0; i < 32; i += 8) {
        const int n = n0 + ty + i;
        const int j = j0 + tx;
        if (n < NNODES) dst[(size_t)n * DIN + j] = __float2bfloat16(tile[tx][ty + i]);
    }
}

__device__ __forceinline__ float bf_lo(unsigned u) {
    union { unsigned v; float f; } c; c.v = u << 16; return c.f;
}
__device__ __forceinline__ float bf_hi(unsigned u) {
    union { unsigned v; float f; } c; c.v = u & 0xffff0000u; return c.f;
}

// ---------------------------------------------------------------------------
// Walk kernel: one 64-lane wave handles TWO tokens with skewed interleaved
// serial chains. Per level, program order is
//   [dot A | reduce A | decide A | issue load A(next)]
//   [dot B | reduce B | decide B | issue load B(next)]
// so each chain's row-load latency is covered by the other chain's compute
// phase (plus 4 waves/SIMD of TLP). No speculative loads -> half the row
// traffic of round 3. Dot arithmetic bit-identical to rounds 2/3.
// ---------------------------------------------------------------------------
__global__ __launch_bounds__(512) void fff_walk2(const float* __restrict__ x,
                                                 const float* __restrict__ w_in,
                                                 int* __restrict__ nd_out,
                                                 float* __restrict__ g_out) {
    const int wid  = (int)((blockIdx.x * blockDim.x + threadIdx.x) >> 6);
    const int lane = (int)(threadIdx.x & 63);
    const int tA = wid * 2;
    const int tB = tA + 1;

    const float4* xrA = reinterpret_cast<const float4*>(x + (size_t)tA * DIN);
    const float4* xrB = reinterpret_cast<const float4*>(x + (size_t)tB * DIN);
    const float4 xA0 = xrA[lane], xA1 = xrA[lane + 64], xA2 = xrA[lane + 128];
    const float4 xB0 = xrB[lane], xB1 = xrB[lane + 64], xB2 = xrB[lane + 128];

    // both chains start at root row 0
    const float4* r0 = reinterpret_cast<const float4*>(w_in);
    float4 cA0 = r0[lane], cA1 = r0[lane + 64], cA2 = r0[lane + 128];
    float4 cB0 = cA0, cB1 = cA1, cB2 = cA2;

    int curA = 0, curB = 0;

#pragma unroll
    for (int d = 0; d <= DEPTH; ++d) {
        // ================= chain A =================
        {
            double p0 = 0.0, p1 = 0.0, p2 = 0.0;
            p0 += (double)xA0.x * cA0.x; p0 += (double)xA0.y * cA0.y;
            p0 += (double)xA0.z * cA0.z; p0 += (double)xA0.w * cA0.w;
            p1 += (double)xA1.x * cA1.x; p1 += (double)xA1.y * cA1.y;
            p1 += (double)xA1.z * cA1.z; p1 += (double)xA1.w * cA1.w;
            p2 += (double)xA2.x * cA2.x; p2 += (double)xA2.y * cA2.y;
            p2 += (double)xA2.z * cA2.z; p2 += (double)xA2.w * cA2.w;
            double part = (p0 + p1) + p2;
#pragma unroll
            for (int off = 32; off >= 1; off >>= 1) part += __shfl_xor(part, off);

            const bool right = (part > 0.0);
            const int  nxt   = 2 * curA + 1 + (right ? 1 : 0);
            if (d < DEPTH) {   // issue next row load immediately (covered by B's phase)
                const float4* wr = reinterpret_cast<const float4*>(w_in + (size_t)nxt * DIN);
                cA0 = wr[lane]; cA1 = wr[lane + 64]; cA2 = wr[lane + 128];
            }
            if (lane == 0) {
                const float lg = (float)part;
                g_out[tA * 12 + d]  = 0.5f * lg * (1.0f + erff(lg * 0.7071067811865476f));
                nd_out[tA * 12 + d] = curA;
            }
            curA = nxt;
        }

        // ================= chain B =================
        {
            double p0 = 0.0, p1 = 0.0, p2 = 0.0;
            p0 += (double)xB0.x * cB0.x; p0 += (double)xB0.y * cB0.y;
            p0 += (double)xB0.z * cB0.z; p0 += (double)xB0.w * cB0.w;
            p1 += (double)xB1.x * cB1.x; p1 += (double)xB1.y * cB1.y;
            p1 += (double)xB1.z * cB1.z; p1 += (double)xB1.w * cB1.w;
            p2 += (double)xB2.x * cB2.x; p2 += (double)xB2.y * cB2.y;
            p2 += (double)xB2.z * cB2.z; p2 += (double)xB2.w * cB2.w;
            double part = (p0 + p1) + p2;
#pragma unroll
            for (int off = 32; off >= 1; off >>= 1) part += __shfl_xor(part, off);

            const bool right = (part > 0.0);
            const int  nxt   = 2 * curB + 1 + (right ? 1 : 0);
            if (d < DEPTH) {   // issue next row load immediately (covered by A's phase)
                const float4* wr = reinterpret_cast<const float4*>(w_in + (size_t)nxt * DIN);
                cB0 = wr[lane]; cB1 = wr[lane + 64]; cB2 = wr[lane + 128];
            }
            if (lane == 0) {
                const float lg = (float)part;
                g_out[tB * 12 + d]  = 0.5f * lg * (1.0f + erff(lg * 0.7071067811865476f));
                nd_out[tB * 12 + d] = curB;
            }
            curB = nxt;
        }
    }
}

// ---------------------------------------------------------------------------
// Gather kernel: one wave per token; 36 fully independent bf16 row loads.
// ---------------------------------------------------------------------------
__global__ __launch_bounds__(256) void fff_gather(const __hip_bfloat16* __restrict__ wT,
                                                  const int* __restrict__ nd_in,
                                                  const float* __restrict__ g_in,
                                                  float* __restrict__ out) {
    const int token = (int)((blockIdx.x * blockDim.x + threadIdx.x) >> 6);
    const int lane  = (int)(threadIdx.x & 63);

    float gv = 0.f; int nv = 0;
    if (lane < 12) {
        gv = g_in[token * 12 + lane];
        nv = nd_in[token * 12 + lane];
    }

    float acc[12];
#pragma unroll
    for (int i = 0; i < 12; ++i) acc[i] = 0.f;

#pragma unroll
    for (int d = 0; d <= DEPTH; ++d) {
        const float gg = __shfl(gv, d);
        const int   nn = __shfl(nv, d);
        const uint2* row = reinterpret_cast<const uint2*>(wT + (size_t)nn * DIN);
#pragma unroll
        for (int k = 0; k < 3; ++k) {
            const uint2 v = row[lane + 64 * k];
            acc[k * 4 + 0] = fmaf(gg, bf_lo(v.x), acc[k * 4 + 0]);
            acc[k * 4 + 1] = fmaf(gg, bf_hi(v.x), acc[k * 4 + 1]);
            acc[k * 4 + 2] = fmaf(gg, bf_lo(v.y), acc[k * 4 + 2]);
            acc[k * 4 + 3] = fmaf(gg, bf_hi(v.y), acc[k * 4 + 3]);
        }
    }

    float4* orow = reinterpret_cast<float4*>(out + (size_t)token * DIN);
#pragma unroll
    for (int k = 0; k < 3; ++k)
        orow[k * 64 + lane] = make_float4(acc[k * 4 + 0], acc[k * 4 + 1],
                                          acc[k * 4 + 2], acc[k * 4 + 3]);
}

// ---------------------------------------------------------------------------
// Fallback (ws too small): round-1 fused kernel with strided f32 w_out reads.
// ---------------------------------------------------------------------------
__global__ __launch_bounds__(256) void fff_fused_fallback(const float* __restrict__ x,
                                                          const float* __restrict__ w_in,
                                                          const float* __restrict__ w_o,
                                                          float* __restrict__ out) {
    const int token = (int)((blockIdx.x * blockDim.x + threadIdx.x) >> 6);
    const int lane  = (int)(threadIdx.x & 63);

    const float4* xr = reinterpret_cast<const float4*>(x + (size_t)token * DIN);
    float4 xv[3];
#pragma unroll
    for (int k = 0; k < 3; ++k) xv[k] = xr[lane + 64 * k];
    float4 acc[3];
#pragma unroll
    for (int k = 0; k < 3; ++k) acc[k] = make_float4(0.f, 0.f, 0.f, 0.f);

    int cur = 0;
#pragma unroll
    for (int d = 0; d <= DEPTH; ++d) {
        const float4* wr = reinterpret_cast<const float4*>(w_in + (size_t)cur * DIN);
        double part = 0.0;
#pragma unroll
        for (int k = 0; k < 3; ++k) {
            const float4 w = wr[lane + 64 * k];
            part += (double)xv[k].x * w.x; part += (double)xv[k].y * w.y;
            part += (double)xv[k].z * w.z; part += (double)xv[k].w * w.w;
        }
#pragma unroll
        for (int off = 32; off >= 1; off >>= 1) part += __shfl_xor(part, off);
        const float logit = (float)part;
        const float gg = 0.5f * logit * (1.0f + erff(logit * 0.7071067811865476f));
#pragma unroll
        for (int k = 0; k < 3; ++k) {
            const int j = (lane + 64 * k) * 4;
            acc[k].x = fmaf(gg, w_o[(size_t)(j + 0) * NNODES + cur], acc[k].x);
            acc[k].y = fmaf(gg, w_o[(size_t)(j + 1) * NNODES + cur], acc[k].y);
            acc[k].z = fmaf(gg, w_o[(size_t)(j + 2) * NNODES + cur], acc[k].z);
            acc[k].w = fmaf(gg, w_o[(size_t)(j + 3) * NNODES + cur], acc[k].w);
        }
        if (d < DEPTH) cur = 2 * cur + 1 + (part > 0.0 ? 1 : 0);
    }
    float4* orow = reinterpret_cast<float4*>(out + (size_t)token * DIN);
#pragma unroll
    for (int k = 0; k < 3; ++k) orow[lane + 64 * k] = acc[k];
}

extern "C" void kernel_launch(void* const* d_in, const int* in_sizes, int n_in,
                              void* d_out, int out_size, void* d_ws, size_t ws_size,
                              hipStream_t stream) {
    const float* x     = (const float*)d_in[0];   // [8192, 768]
    const float* w_in  = (const float*)d_in[1];   // [4095, 768]
    const float* w_out = (const float*)d_in[2];   // [768, 4095]
    float*       out   = (float*)d_out;           // [8192, 768]

    const size_t wT_bytes = (size_t)NNODES * DIN * sizeof(__hip_bfloat16);  // 6,289,920
    const size_t nd_bytes = (size_t)NTOK * 12 * sizeof(int);                // 393,216
    const size_t g_bytes  = (size_t)NTOK * 12 * sizeof(float);              // 393,216
    const size_t need = wT_bytes + nd_bytes + g_bytes;                      // ~7.08 MB

    if (ws_size >= need) {
        char* ws = (char*)d_ws;
        __hip_bfloat16* wT = (__hip_bfloat16*)ws;
        int*   nd = (int*)(ws + wT_bytes);
        float* g  = (float*)(ws + wT_bytes + nd_bytes);

        dim3 tb(32, 8);
        dim3 tg((NNODES + 31) / 32, DIN / 32);
        hipLaunchKernelGGL(fff_transpose_bf16, tg, tb, 0, stream, w_out, wT);
        // 8192 tokens / 2 per wave = 4096 waves; 512 threads = 8 waves/block
        hipLaunchKernelGGL(fff_walk2, dim3(512), dim3(512), 0, stream, x, w_in, nd, g);
        hipLaunchKernelGGL(fff_gather, dim3(NTOK / 4), dim3(256), 0, stream, wT, nd, g, out);
    } else {
        hipLaunchKernelGGL(fff_fused_fallback, dim3(NTOK / 4), dim3(256), 0, stream,
                           x, w_in, w_out, out);
    }
}